// Round 3
// baseline (794.399 us; speedup 1.0000x reference)
//
#include <hip/hip_runtime.h>

#define B_   64
#define T_   1024
#define D_   128
#define SCALE_ 0.08838834764831845f
#define FILL_  (-4294967295.0f)
#define OBS  68   // O-reduction row stride (floats): 272B = 16B-aligned, 68%32=4 banks

typedef __attribute__((ext_vector_type(8))) short short8v;
typedef __attribute__((ext_vector_type(4))) float f32x4;

#define MFMA16(A,Bv,C) __builtin_amdgcn_mfma_f32_16x16x32_bf16((A),(Bv),(C),0,0,0)

// truncation-split: f ~= hi + lo with hi,lo bf16 (error ~2^-17 rel)
__device__ __forceinline__ void split8(const float f[8], short8v& h, short8v& l) {
#pragma unroll
    for (int i = 0; i < 8; ++i) {
        const unsigned int u = __float_as_uint(f[i]);
        h[i] = (short)(u >> 16);
        const float r = f[i] - __uint_as_float(u & 0xffff0000u);
        l[i] = (short)(__float_as_uint(r) >> 16);
    }
}
__device__ __forceinline__ unsigned int packsplit(float f) {
    const unsigned int u = __float_as_uint(f);
    const unsigned int hi = u >> 16;
    const float r = f - __uint_as_float(u & 0xffff0000u);
    const unsigned int lo = __float_as_uint(r) >> 16;
    return hi | (lo << 16);
}

// One block per (batch, 32-row q-tile); 512 threads = 8 waves.
// QK^T: wave w owns k-cols [w*128, w*128+128). MFMA 16x16x32 bf16, hi/lo split x3.
// PV:   waves split k (64 k-rows per wave per 512-chunk); P exchanged via LDS
//       [k][row] u32 (hi|lo<<16), pad 33 -> 2-way (free) bank aliasing on A reads.
// Epilogue: cross-wave O reduce via LDS rows padded to OBS=68 floats (16B-aligned).
__global__ __launch_bounds__(512)
void mha_kernel(const float* __restrict__ Kp, const float* __restrict__ Vp,
                const float* __restrict__ Qp, const unsigned char* __restrict__ Mp,
                const float* __restrict__ QMp, float* __restrict__ Orp,
                float* __restrict__ Oap)
{
    // 17408 u32 = 69632 B: covers Pbuf view (512*33 u32) and Ob view (8*32*68 f32)
    __shared__ __align__(16) unsigned int Pbuf[8 * 32 * OBS];
    __shared__ float redA[8 * 32];
    __shared__ float redB[8 * 32];

    const int tid  = threadIdx.x;
    const int w    = tid >> 6;
    const int lane = tid & 63;
    const int g    = lane >> 4;
    const int c    = lane & 15;
    const int b    = blockIdx.x >> 5;
    const int q0   = (blockIdx.x & 31) << 5;

    // ---- mask dtype auto-detect (u8 bool vs i32) ----
    const unsigned int* mw = (const unsigned int*)Mp;
    unsigned int bad = 0u;
#pragma unroll
    for (int i = 0; i < 16; ++i) bad |= (unsigned int)(mw[i] > 1u);
    const bool m32 = (bad == 0u);

    const size_t bt = (size_t)b * T_;

    // =================== QK^T ===================
    f32x4 acc[2][8];
#pragma unroll
    for (int mt = 0; mt < 2; ++mt)
#pragma unroll
        for (int nt = 0; nt < 8; ++nt) acc[mt][nt] = (f32x4)0.f;

#pragma unroll
    for (int ks = 0; ks < 4; ++ks) {
        short8v qh[2], ql[2];
#pragma unroll
        for (int mt = 0; mt < 2; ++mt) {
            const float* qp = Qp + (bt + q0 + mt*16 + c) * D_ + ks*32 + g*8;
            float f[8];
#pragma unroll
            for (int i = 0; i < 8; ++i) f[i] = qp[i];
            split8(f, qh[mt], ql[mt]);
        }
#pragma unroll
        for (int nt = 0; nt < 8; ++nt) {
            const float* kp = Kp + (bt + w*128 + nt*16 + c) * D_ + ks*32 + g*8;
            float f[8];
#pragma unroll
            for (int i = 0; i < 8; ++i) f[i] = kp[i];
            short8v kh, kl;
            split8(f, kh, kl);
#pragma unroll
            for (int mt = 0; mt < 2; ++mt) {
                acc[mt][nt] = MFMA16(qh[mt], kh, acc[mt][nt]);
                acc[mt][nt] = MFMA16(qh[mt], kl, acc[mt][nt]);
                acc[mt][nt] = MFMA16(ql[mt], kh, acc[mt][nt]);
            }
        }
    }

    // =================== mask + scale + softmax ===================
    float rmax[2][4];
#pragma unroll
    for (int mt = 0; mt < 2; ++mt)
#pragma unroll
    for (int rg = 0; rg < 4; ++rg) {
        const int row = mt*16 + g*4 + rg;
        const size_t mrow = (bt + q0 + row) * (size_t)T_ + w*128;
        float rm = -3.0e38f;
        if (m32) {
            const int* mi = (const int*)Mp;
#pragma unroll
            for (int nt = 0; nt < 8; ++nt) {
                float s = acc[mt][nt][rg] * SCALE_;
                if (mi[mrow + nt*16 + c]) s = FILL_;
                acc[mt][nt][rg] = s;
                rm = fmaxf(rm, s);
            }
        } else {
#pragma unroll
            for (int nt = 0; nt < 8; ++nt) {
                float s = acc[mt][nt][rg] * SCALE_;
                if (Mp[mrow + nt*16 + c]) s = FILL_;
                acc[mt][nt][rg] = s;
                rm = fmaxf(rm, s);
            }
        }
        rmax[mt][rg] = rm;
    }
#pragma unroll
    for (int mt = 0; mt < 2; ++mt)
#pragma unroll
    for (int rg = 0; rg < 4; ++rg)
#pragma unroll
        for (int off = 1; off < 16; off <<= 1)
            rmax[mt][rg] = fmaxf(rmax[mt][rg], __shfl_xor(rmax[mt][rg], off, 64));
    if (c == 0) {
#pragma unroll
        for (int mt = 0; mt < 2; ++mt)
#pragma unroll
        for (int rg = 0; rg < 4; ++rg)
            redA[w*32 + mt*16 + g*4 + rg] = rmax[mt][rg];
    }
    __syncthreads();
    float rsum[2][4];
#pragma unroll
    for (int mt = 0; mt < 2; ++mt)
#pragma unroll
    for (int rg = 0; rg < 4; ++rg) {
        const int row = mt*16 + g*4 + rg;
        float m = redA[row];
#pragma unroll
        for (int w2 = 1; w2 < 8; ++w2) m = fmaxf(m, redA[w2*32 + row]);
        float s = 0.f;
#pragma unroll
        for (int nt = 0; nt < 8; ++nt) {
            const float e = __expf(acc[mt][nt][rg] - m);
            acc[mt][nt][rg] = e;
            s += e;
        }
#pragma unroll
        for (int off = 1; off < 16; off <<= 1) s += __shfl_xor(s, off, 64);
        rsum[mt][rg] = s;
    }
    if (c == 0) {
#pragma unroll
        for (int mt = 0; mt < 2; ++mt)
#pragma unroll
        for (int rg = 0; rg < 4; ++rg)
            redB[w*32 + mt*16 + g*4 + rg] = rsum[mt][rg];
    }
    __syncthreads();

    // finalize p = e * query_mask / sum; store attn; pack hi/lo for PV
    unsigned int pk[2][8][4];
#pragma unroll
    for (int mt = 0; mt < 2; ++mt)
#pragma unroll
    for (int rg = 0; rg < 4; ++rg) {
        const int row = mt*16 + g*4 + rg;
        float ssum = redB[row];
#pragma unroll
        for (int w2 = 1; w2 < 8; ++w2) ssum += redB[w2*32 + row];
        const float inv = QMp[bt + q0 + row] / ssum;
        const size_t arow = (bt + q0 + row) * (size_t)T_ + w*128;
#pragma unroll
        for (int nt = 0; nt < 8; ++nt) {
            const float p = acc[mt][nt][rg] * inv;
            Oap[arow + nt*16 + c] = p;
            pk[mt][nt][rg] = packsplit(p);
        }
    }

    // =================== PV ===================
    f32x4 o[2][8];
#pragma unroll
    for (int mt = 0; mt < 2; ++mt)
#pragma unroll
        for (int nt = 0; nt < 8; ++nt) o[mt][nt] = (f32x4)0.f;

#pragma unroll
    for (int chunk = 0; chunk < 2; ++chunk) {
        __syncthreads();                      // Pbuf WAR vs previous chunk's reads
        if ((w >> 2) == chunk) {
#pragma unroll
            for (int mt = 0; mt < 2; ++mt)
#pragma unroll
            for (int nt = 0; nt < 8; ++nt)
#pragma unroll
            for (int rg = 0; rg < 4; ++rg) {
                const int kl  = (w & 3)*128 + nt*16 + c;
                const int row = mt*16 + g*4 + rg;
                Pbuf[kl*33 + row] = pk[mt][nt][rg];
            }
        }
        __syncthreads();
#pragma unroll
        for (int ks2 = 0; ks2 < 2; ++ks2) {
            const int klb = w*64 + ks2*32;    // this wave's local k base
            short8v ph[2], pl[2];
#pragma unroll
            for (int mt = 0; mt < 2; ++mt) {
                const int base = (klb + g*8)*33 + mt*16 + c;
#pragma unroll
                for (int i = 0; i < 8; ++i) {
                    const unsigned int x = Pbuf[base + i*33];
                    ph[mt][i] = (short)(x & 0xffffu);
                    pl[mt][i] = (short)(x >> 16);
                }
            }
#pragma unroll
            for (int nt = 0; nt < 8; ++nt) {
                const float* vp = Vp + (bt + chunk*512 + klb + g*8) * D_ + nt*16 + c;
                float f[8];
#pragma unroll
                for (int i = 0; i < 8; ++i) f[i] = vp[(size_t)i * D_];
                short8v vh, vl;
                split8(f, vh, vl);
#pragma unroll
                for (int mt = 0; mt < 2; ++mt) {
                    o[mt][nt] = MFMA16(ph[mt], vh, o[mt][nt]);
                    o[mt][nt] = MFMA16(ph[mt], vl, o[mt][nt]);
                    o[mt][nt] = MFMA16(pl[mt], vh, o[mt][nt]);
                }
            }
        }
    }

    // =================== cross-wave O reduction + result write ===================
    float* Ob = (float*)Pbuf;                 // [8][32][OBS] f32, OBS=68 (16B-aligned rows)
#pragma unroll
    for (int half = 0; half < 2; ++half) {
        __syncthreads();                      // WAR vs PV reads / previous half
#pragma unroll
        for (int mt = 0; mt < 2; ++mt)
#pragma unroll
        for (int nq = 0; nq < 4; ++nq) {
            const int nt = half*4 + nq;
#pragma unroll
            for (int rg = 0; rg < 4; ++rg) {
                const int row = mt*16 + g*4 + rg;
                Ob[(w*32 + row)*OBS + nq*16 + c] = o[mt][nt][rg];
            }
        }
        __syncthreads();
        {
            const int row = tid >> 4;
            const int d0  = (tid & 15) << 2;
            float s0 = 0.f, s1 = 0.f, s2 = 0.f, s3 = 0.f;
#pragma unroll
            for (int w2 = 0; w2 < 8; ++w2) {
                const float* p = &Ob[(w2*32 + row)*OBS + d0];   // 16B-aligned: OBS*4=272
                s0 += p[0]; s1 += p[1]; s2 += p[2]; s3 += p[3];
            }
            float4 r; r.x = s0; r.y = s1; r.z = s2; r.w = s3;
            *(float4*)&Orp[(bt + q0 + row) * D_ + half*64 + d0] = r;
        }
    }
}

extern "C" void kernel_launch(void* const* d_in, const int* in_sizes, int n_in,
                              void* d_out, int out_size, void* d_ws, size_t ws_size,
                              hipStream_t stream)
{
    const float* Kp  = (const float*)d_in[0];                 // key   [B,T,D]
    const float* Vp  = (const float*)d_in[1];                 // value [B,T,D]
    const float* Qp  = (const float*)d_in[2];                 // query [B,T,D]
    const unsigned char* Mp = (const unsigned char*)d_in[3];  // mask  [B,T,T]
    const float* QMp = (const float*)d_in[4];                 // query_mask [B,T,1]
    float* Orp = (float*)d_out;                               // result [B,T,D] first
    float* Oap = Orp + (size_t)B_ * T_ * D_;                  // then attn [B,T,T]

    hipLaunchKernelGGL(mha_kernel, dim3(B_ * 32), dim3(512), 0, stream,
                       Kp, Vp, Qp, Mp, QMp, Orp, Oap);
}